// Round 10
// baseline (1881.351 us; speedup 1.0000x reference)
//
#include <hip/hip_runtime.h>
#include <cstddef>
#include <cstdint>

// Grouped GRU via MFMA: B=32, C=512, T=2000, G=8, I=64, H=64
// Phase 1 (gru_xproj): xp[t] = scaled(W_ih x_t + biases), f32, fragment layout.
//   Scaling: r,z rows x log2(e); n rows x 2*log2(e)  -> epilogue exp == v_exp_f32.
// Phase 2 (gru_scan_mfma, 8 blocks x 512 thr): TWO (g,bt) recurrence units per
//   block (waves 0-3 / 4-7) -> 2 waves per SIMD, cross-hiding ds_read/MFMA/TRANS
//   latency that was fully exposed at 1 wave/SIMD (R9: 1065 cyc/step, 440 issue).
// Per unit step: 6x mfma_f32_16x16x32_f16, in-register h carry + LDS h exchange.

typedef _Float16 f16x8 __attribute__((ext_vector_type(8)));
typedef _Float16 f16x2 __attribute__((ext_vector_type(2)));
typedef float    f32x4 __attribute__((ext_vector_type(4)));

constexpr int B_ = 32, C_ = 512, T_ = 2000, G_ = 8, I_ = 64, H_ = 64, K3_ = 192;
constexpr int GB_ = 16;            // (g, bt) units
constexpr int XP_STRIDE = 3072;    // f32 per (gb, t): 192 rows x 16 batches
constexpr int FL_ = 8;             // flush group (steps held in registers)
constexpr float L2E_ = 1.4426950408889634f;

#define BARRIER_LGKM() asm volatile("s_waitcnt lgkmcnt(0)\n\ts_barrier" ::: "memory")

__device__ __forceinline__ f32x4 mfma16(f16x8 a, f16x8 b, f32x4 c) {
    return __builtin_amdgcn_mfma_f32_16x16x32_f16(a, b, c, 0, 0, 0);
}

__device__ __forceinline__ f16x8 pack8(float a0,float a1,float a2,float a3,
                                       float a4,float a5,float a6,float a7) {
    auto p0 = __builtin_amdgcn_cvt_pkrtz(a0, a1);   // __fp16x2, 4 bytes
    auto p1 = __builtin_amdgcn_cvt_pkrtz(a2, a3);
    auto p2 = __builtin_amdgcn_cvt_pkrtz(a4, a5);
    auto p3 = __builtin_amdgcn_cvt_pkrtz(a6, a7);
    int4 t; t.x = __builtin_bit_cast(int, p0); t.y = __builtin_bit_cast(int, p1);
            t.z = __builtin_bit_cast(int, p2); t.w = __builtin_bit_cast(int, p3);
    return __builtin_bit_cast(f16x8, t);
}

__device__ __forceinline__ float exp2_f(float x) {
#if __has_builtin(__builtin_amdgcn_exp2f)
    return __builtin_amdgcn_exp2f(x);
#else
    return exp2f(x);
#endif
}
// Inputs PRE-SCALED: y = x*log2e (sigmoid), y = 2x*log2e (tanh)
__device__ __forceinline__ float sigmoid_s(float y) {
    return __builtin_amdgcn_rcpf(1.0f + exp2_f(-y));
}
__device__ __forceinline__ float tanh_s(float y) {
    return 1.0f - 2.0f * __builtin_amdgcn_rcpf(exp2_f(y) + 1.0f);
}

// ---------------- Phase 1: x-projection into fragment layout ----------------
template <int TC>
__global__ __launch_bounds__(256, 1)
void gru_xproj(const float* __restrict__ x,
               const float* __restrict__ w_ih,
               const float* __restrict__ b_ih,
               const float* __restrict__ b_hh,
               float* __restrict__ xp, int t0, int tlen)
{
    const int gb = blockIdx.y, g = gb >> 1, bt = gb & 1;
    const int tbase = t0 + blockIdx.x * TC;
    const int tid = threadIdx.x;
    const int w = tid >> 6, lw = tid & 63, p = lw >> 4, c = lw & 15;
    const int b_glob = bt * 16 + c;

    // A-frags: W_ih rows 64*mt + 16*w + c, scaled (r,z: L2E; n: 2*L2E)
    f16x8 WI[3][2];
    #pragma unroll
    for (int mt = 0; mt < 3; ++mt) {
        const float s = (mt < 2) ? L2E_ : 2.0f * L2E_;
        const float* row = w_ih + ((size_t)g * K3_ + 64 * mt + 16 * w + c) * I_;
        #pragma unroll
        for (int kt = 0; kt < 2; ++kt) {
            const float4* p4 = reinterpret_cast<const float4*>(row + 32 * kt + 8 * p);
            float4 A = p4[0], Bq = p4[1];
            WI[mt][kt] = pack8(s*A.x, s*A.y, s*A.z, s*A.w, s*Bq.x, s*Bq.y, s*Bq.z, s*Bq.w);
        }
    }
    // Bias C-inits (scaled): r,z get (b_ih+b_hh)*L2E; n gets b_ih*2*L2E
    f32x4 biasR, biasZ, biasN;
    #pragma unroll
    for (int r = 0; r < 4; ++r) {
        const int row = 16 * w + 4 * p + r;
        biasR[r] = (b_ih[g * K3_ + row]      + b_hh[g * K3_ + row])      * L2E_;
        biasZ[r] = (b_ih[g * K3_ + 64 + row] + b_hh[g * K3_ + 64 + row]) * L2E_;
        biasN[r] = b_ih[g * K3_ + 128 + row] * 2.0f * L2E_;
    }

    const float* xb = x + ((size_t)b_glob * C_ + g * I_) * T_;   // + q*T_ + t
    float* xpo = xp + ((size_t)gb * tlen + (tbase - t0)) * XP_STRIDE + tid * 12;

    for (int tt = 0; tt < TC / 4; ++tt) {
        float xq[2][8][4];
        #pragma unroll
        for (int s = 0; s < 2; ++s)
            #pragma unroll
            for (int e = 0; e < 8; ++e) {
                const int q = 32 * s + 8 * p + e;
                float4 v = *reinterpret_cast<const float4*>(xb + (size_t)q * T_ + tbase + tt * 4);
                xq[s][e][0] = v.x; xq[s][e][1] = v.y; xq[s][e][2] = v.z; xq[s][e][3] = v.w;
            }
        #pragma unroll
        for (int tl = 0; tl < 4; ++tl) {
            f16x8 B0 = pack8(xq[0][0][tl], xq[0][1][tl], xq[0][2][tl], xq[0][3][tl],
                             xq[0][4][tl], xq[0][5][tl], xq[0][6][tl], xq[0][7][tl]);
            f16x8 B1 = pack8(xq[1][0][tl], xq[1][1][tl], xq[1][2][tl], xq[1][3][tl],
                             xq[1][4][tl], xq[1][5][tl], xq[1][6][tl], xq[1][7][tl]);
            f32x4 aR = mfma16(WI[0][0], B0, biasR); aR = mfma16(WI[0][1], B1, aR);
            f32x4 aZ = mfma16(WI[1][0], B0, biasZ); aZ = mfma16(WI[1][1], B1, aZ);
            f32x4 aN = mfma16(WI[2][0], B0, biasN); aN = mfma16(WI[2][1], B1, aN);
            float* o = xpo + (size_t)(tt * 4 + tl) * XP_STRIDE;
            *reinterpret_cast<float4*>(o + 0) = make_float4(aR[0], aR[1], aR[2], aR[3]);
            *reinterpret_cast<float4*>(o + 4) = make_float4(aZ[0], aZ[1], aZ[2], aZ[3]);
            *reinterpret_cast<float4*>(o + 8) = make_float4(aN[0], aN[1], aN[2], aN[3]);
        }
    }
}

// ---------------- Phase 2: MFMA scan (2 units per block) ----------------
struct XPQ { f32x4 r, z, n; };
__device__ __forceinline__ XPQ ld_xp(const float* base, int tl) {
    const float4* p4 = reinterpret_cast<const float4*>(base + (size_t)tl * XP_STRIDE);
    float4 a = p4[0], b = p4[1], c = p4[2];
    XPQ q;
    q.r = f32x4{a.x, a.y, a.z, a.w};
    q.z = f32x4{b.x, b.y, b.z, b.w};
    q.n = f32x4{c.x, c.y, c.z, c.w};
    return q;
}

__global__ __launch_bounds__(512, 1)
void gru_scan_mfma(const float* __restrict__ xp,
                   const float* __restrict__ h0,
                   const float* __restrict__ w_hh,
                   const float* __restrict__ b_hh,
                   float* __restrict__ out,
                   float* __restrict__ h_state,
                   int t0, int tlen)
{
    const int tid = threadIdx.x;            // 0..511
    const int unit = tid >> 8;              // 0/1: which recurrence unit
    const int tidu = tid & 255;
    const int gb = 2 * blockIdx.x + unit, g = gb >> 1, bt = gb & 1;
    const int w = tidu >> 6, lw = tidu & 63, p = lw >> 4, c = lw & 15;
    const int q0 = 16 * w + 4 * p;
    const int b_glob = bt * 16 + c;

    // h^T planes per unit: halfidx(b=c, q) = c*64 + (q ^ ((c&7)<<3))
    __shared__ __align__(16) _Float16 h_lds[2][2][1024];   // [buf][unit][...]

    // A-frags: W_hh rows 64*mt + 16*w + c, scaled like xproj
    f16x8 WH[3][2];
    #pragma unroll
    for (int mt = 0; mt < 3; ++mt) {
        const float s = (mt < 2) ? L2E_ : 2.0f * L2E_;
        const float* row = w_hh + ((size_t)g * K3_ + 64 * mt + 16 * w + c) * H_;
        #pragma unroll
        for (int kt = 0; kt < 2; ++kt) {
            const float4* p4 = reinterpret_cast<const float4*>(row + 32 * kt + 8 * p);
            float4 A = p4[0], Bq = p4[1];
            WH[mt][kt] = pack8(s*A.x, s*A.y, s*A.z, s*A.w, s*Bq.x, s*Bq.y, s*Bq.z, s*Bq.w);
        }
    }
    f32x4 BHN;   // n-gate C-init = b_hh n-rows, scaled
    #pragma unroll
    for (int r = 0; r < 4; ++r) BHN[r] = b_hh[g * K3_ + 128 + q0 + r] * 2.0f * L2E_;

    // h carry (f32, C layout)
    float hC[4];
    if (t0 == 0) {
        #pragma unroll
        for (int r = 0; r < 4; ++r) hC[r] = h0[((size_t)g * B_ + b_glob) * H_ + q0 + r];
    } else {
        #pragma unroll
        for (int r = 0; r < 4; ++r) hC[r] = h_state[gb * 1024 + tidu * 4 + r];
    }

    const int swz_w = c * 64 + (q0 ^ ((c & 7) << 3));               // write (4 halves)
    const int rb0 = c * 128 + 16 * ((p)     ^ (c & 7));             // B0 byte offset
    const int rb1 = c * 128 + 16 * ((4 + p) ^ (c & 7));             // B1 byte offset
    {
        f16x2 lo{(_Float16)hC[0], (_Float16)hC[1]};
        f16x2 hi{(_Float16)hC[2], (_Float16)hC[3]};
        int2 v; v.x = __builtin_bit_cast(int, lo); v.y = __builtin_bit_cast(int, hi);
        *reinterpret_cast<int2*>(reinterpret_cast<char*>(&h_lds[0][unit][0]) + 2 * swz_w) = v;
    }

    float* outp = out + ((size_t)b_glob * C_ + g * 64 + q0) * T_;   // + r*T_ + t
    const float* xpl = xp + ((size_t)gb * tlen) * XP_STRIDE + tidu * 12;

    float hist[4][FL_];   // 8-step output history (static indices)

    // 4 rotating prefetch slots
    XPQ qs[4];
    qs[0] = ld_xp(xpl, 0);
    qs[1] = ld_xp(xpl, 1);
    qs[2] = ld_xp(xpl, 2);
    qs[3] = ld_xp(xpl, 3);
    __syncthreads();   // publish h_lds[0] (one-time full drain is fine)

    // One scan step: consume slot S (= U&3); refill AFTER epilogue (post-use).
    #define STEP_U(U) do {                                                        \
        const int S = (U) & 3;                                                    \
        const int rdbuf = (U) & 1;                                                \
        char* rbase = reinterpret_cast<char*>(&h_lds[rdbuf][unit][0]);            \
        f16x8 B0 = *reinterpret_cast<const f16x8*>(rbase + rb0);                  \
        f16x8 B1 = *reinterpret_cast<const f16x8*>(rbase + rb1);                  \
        f32x4 aR = mfma16(WH[0][0], B0, qs[S].r); aR = mfma16(WH[0][1], B1, aR);  \
        f32x4 aZ = mfma16(WH[1][0], B0, qs[S].z); aZ = mfma16(WH[1][1], B1, aZ);  \
        f32x4 aN = mfma16(WH[2][0], B0, BHN);     aN = mfma16(WH[2][1], B1, aN);  \
        _Pragma("unroll")                                                         \
        for (int r = 0; r < 4; ++r) {                                             \
            float rr = sigmoid_s(aR[r]);                                          \
            float zz = sigmoid_s(aZ[r]);                                          \
            float nn = tanh_s(qs[S].n[r] + rr * aN[r]);                           \
            hC[r] = nn + zz * (hC[r] - nn);                                       \
            hist[r][U] = hC[r];                                                   \
        }                                                                         \
        f16x2 lo{(_Float16)hC[0], (_Float16)hC[1]};                               \
        f16x2 hi{(_Float16)hC[2], (_Float16)hC[3]};                               \
        int2 v; v.x = __builtin_bit_cast(int, lo); v.y = __builtin_bit_cast(int, hi); \
        *reinterpret_cast<int2*>(reinterpret_cast<char*>(&h_lds[rdbuf ^ 1][unit][0]) + 2 * swz_w) = v; \
        int tln = tg + (U) + 4; if (tln > tlen - 1) tln = tlen - 1;               \
        qs[S] = ld_xp(xpl, tln);  /* refill for step tg+U+4 */                    \
        BARRIER_LGKM();                                                           \
    } while (0)

    const int ngrp = tlen / FL_;
    for (int grp = 0; grp < ngrp; ++grp) {
        const int tg = grp * FL_;
        STEP_U(0); STEP_U(1); STEP_U(2); STEP_U(3);
        STEP_U(4); STEP_U(5); STEP_U(6); STEP_U(7);

        // Coalesced flush: 4 rows x 2 dwordx4 (full 64B lines per row-pair)
        #pragma unroll
        for (int r = 0; r < 4; ++r) {
            float* po = outp + (size_t)r * T_ + (t0 + tg);
            *reinterpret_cast<float4*>(po + 0) = make_float4(hist[r][0], hist[r][1], hist[r][2], hist[r][3]);
            *reinterpret_cast<float4*>(po + 4) = make_float4(hist[r][4], hist[r][5], hist[r][6], hist[r][7]);
        }
    }
    #undef STEP_U

    #pragma unroll
    for (int r = 0; r < 4; ++r) h_state[gb * 1024 + tidu * 4 + r] = hC[r];
}

// ---------------- Host ----------------
extern "C" void kernel_launch(void* const* d_in, const int* in_sizes, int n_in,
                              void* d_out, int out_size, void* d_ws, size_t ws_size,
                              hipStream_t stream)
{
    const float* x    = (const float*)d_in[0];
    const float* h0   = (const float*)d_in[1];
    const float* w_ih = (const float*)d_in[2];
    const float* w_hh = (const float*)d_in[3];
    const float* b_ih = (const float*)d_in[4];
    const float* b_hh = (const float*)d_in[5];
    float* out = (float*)d_out;

    const size_t HSTATE_BYTES = 65536;
    // tlen: multiple of 8, divides 2000 -> {400, 200, 40, 8}
    const int cand[4] = {400, 200, 40, 8};
    int tlen = 8;
    for (int i = 0; i < 4; ++i) {
        size_t need = (size_t)cand[i] * GB_ * XP_STRIDE * 4 + HSTATE_BYTES;
        if (need <= ws_size) { tlen = cand[i]; break; }
    }
    const int TC = 8;
    float* xp = (float*)d_ws;
    float* h_state = (float*)((char*)d_ws + (size_t)tlen * GB_ * XP_STRIDE * 4);

    for (int t0 = 0; t0 < T_; t0 += tlen) {
        dim3 pg(tlen / TC, GB_);
        gru_xproj<8><<<pg, 256, 0, stream>>>(x, w_ih, b_ih, b_hh, xp, t0, tlen);
        gru_scan_mfma<<<8, 512, 0, stream>>>(xp, h0, w_hh, b_hh, out, h_state, t0, tlen);
    }
}

// Round 11
// 890.978 us; speedup vs baseline: 2.1116x; 2.1116x over previous
//
#include <hip/hip_runtime.h>
#include <cstddef>
#include <cstdint>

// Grouped GRU: B=32, C=512, T=2000, G=8, I=64, H=64
// Phase 1 (gru_xproj, 256 blocks): xp[t,u,j] = exp2-prescaled pre-activations
//   (W_ih x_t + biases) in 3 SoA planes (r,z,n), MFMA 16x16x32, LDS-staged x.
// Phase 2 (gru_scan_lane, 64 blocks x 4 INDEPENDENT waves): one wave per
//   (b,g) unit. Lane j = element j. NO barrier: h lives as 64 fp16 in a
//   per-wave LDS line; reads are lane-uniform (broadcast); wave-sync by
//   s_waitcnt lgkmcnt(0). 96 fdot2/step (6 chains), 6 TRANS/step/wave.
//   Law learned in R10: scan time = T x single-unit step cycles. This
//   structure minimizes the step: no barrier skew, no cross-wave exchange.

typedef _Float16 f16x8 __attribute__((ext_vector_type(8)));
typedef _Float16 h2    __attribute__((ext_vector_type(2)));
typedef float    f32x4 __attribute__((ext_vector_type(4)));

constexpr int B_ = 32, C_ = 512, T_ = 2000, G_ = 8, H_ = 64, K3_ = 192;
constexpr int NU_ = 256;                 // units = B*G
constexpr float L2E_  = 1.4426950408889634f;
constexpr float L2E2_ = 2.8853900817779268f;

__device__ __forceinline__ f32x4 mfma16(f16x8 a, f16x8 b, f32x4 c) {
    return __builtin_amdgcn_mfma_f32_16x16x32_f16(a, b, c, 0, 0, 0);
}
__device__ __forceinline__ f16x8 pack8(float a0,float a1,float a2,float a3,
                                       float a4,float a5,float a6,float a7) {
    auto p0 = __builtin_amdgcn_cvt_pkrtz(a0, a1);
    auto p1 = __builtin_amdgcn_cvt_pkrtz(a2, a3);
    auto p2 = __builtin_amdgcn_cvt_pkrtz(a4, a5);
    auto p3 = __builtin_amdgcn_cvt_pkrtz(a6, a7);
    int4 t; t.x = __builtin_bit_cast(int, p0); t.y = __builtin_bit_cast(int, p1);
            t.z = __builtin_bit_cast(int, p2); t.w = __builtin_bit_cast(int, p3);
    return __builtin_bit_cast(f16x8, t);
}
__device__ __forceinline__ float exp2_f(float x) {
#if __has_builtin(__builtin_amdgcn_exp2f)
    return __builtin_amdgcn_exp2f(x);
#else
    return exp2f(x);
#endif
}
__device__ __forceinline__ float fdot2_(h2 a, h2 b, float c) {
#if __has_builtin(__builtin_amdgcn_fdot2)
    return __builtin_amdgcn_fdot2(a, b, c, false);
#else
    return fmaf((float)a[0], (float)b[0], fmaf((float)a[1], (float)b[1], c));
#endif
}

// ---------------- Phase 1: x-projection -> SoA planes ----------------
__global__ __launch_bounds__(256, 1)
void gru_xproj(const float* __restrict__ x,
               const float* __restrict__ w_ih,
               const float* __restrict__ b_ih,
               const float* __restrict__ b_hh,
               float* __restrict__ xp, int t0, int tlen)
{
    const int u = blockIdx.x, b = u >> 3, g = u & 7;
    const int tid = threadIdx.x;
    const int w = tid >> 6, lw = tid & 63, p = lw >> 4, c = lw & 15;
    const int gK = g * K3_;

    __shared__ float xs[64][17];   // [ch][t-local], padded

    // A-frags: W_ih rows 64*mt + 16*w + c; k = 32*kt + 8*p + e (R7-validated pair)
    f16x8 WI[3][2];
    #pragma unroll
    for (int mt = 0; mt < 3; ++mt) {
        const float s = (mt < 2) ? L2E_ : L2E2_;
        const float* row = w_ih + ((size_t)gK + 64 * mt + 16 * w + c) * 64;
        #pragma unroll
        for (int kt = 0; kt < 2; ++kt) {
            const float4* p4 = reinterpret_cast<const float4*>(row + 32 * kt + 8 * p);
            float4 A = p4[0], Bq = p4[1];
            WI[mt][kt] = pack8(s*A.x, s*A.y, s*A.z, s*A.w, s*Bq.x, s*Bq.y, s*Bq.z, s*Bq.w);
        }
    }
    f32x4 biasR, biasZ, biasN;
    #pragma unroll
    for (int r = 0; r < 4; ++r) {
        const int rg = 16 * w + 4 * p + r;
        biasR[r] = (b_ih[gK + rg]       + b_hh[gK + rg])       * L2E_;
        biasZ[r] = (b_ih[gK + 64 + rg]  + b_hh[gK + 64 + rg])  * L2E_;
        biasN[r] = b_ih[gK + 128 + rg] * L2E2_;
    }

    const float* xb = x + ((size_t)b * C_ + g * 64) * T_;
    const int sch = tid >> 2, stq = (tid & 3) * 4;   // staging: ch, t-quad
    const size_t PL = (size_t)tlen * NU_ * 64;
    const int niter = (tlen + 15) / 16;

    for (int tt = 0; tt < niter; ++tt) {
        const int tb = t0 + tt * 16;
        int tg_ = tb + stq; if (tg_ > T_ - 4) tg_ = T_ - 4;   // clamp (masked cols only)
        float4 xv = *reinterpret_cast<const float4*>(xb + (size_t)sch * T_ + tg_);
        __syncthreads();   // prev-iter xs reads done
        xs[sch][stq+0] = xv.x; xs[sch][stq+1] = xv.y;
        xs[sch][stq+2] = xv.z; xs[sch][stq+3] = xv.w;
        __syncthreads();   // xs ready

        f16x8 B0 = pack8(xs[8*p+0][c], xs[8*p+1][c], xs[8*p+2][c], xs[8*p+3][c],
                         xs[8*p+4][c], xs[8*p+5][c], xs[8*p+6][c], xs[8*p+7][c]);
        f16x8 B1 = pack8(xs[32+8*p+0][c], xs[32+8*p+1][c], xs[32+8*p+2][c], xs[32+8*p+3][c],
                         xs[32+8*p+4][c], xs[32+8*p+5][c], xs[32+8*p+6][c], xs[32+8*p+7][c]);
        f32x4 aR = mfma16(WI[0][0], B0, biasR); aR = mfma16(WI[0][1], B1, aR);
        f32x4 aZ = mfma16(WI[1][0], B0, biasZ); aZ = mfma16(WI[1][1], B1, aZ);
        f32x4 aN = mfma16(WI[2][0], B0, biasN); aN = mfma16(WI[2][1], B1, aN);

        const int tloc = tt * 16 + c;
        if (tloc < tlen) {
            const size_t o = ((size_t)tloc * NU_ + u) * 64 + 16 * w + 4 * p;
            *reinterpret_cast<float4*>(xp + o)          = make_float4(aR[0], aR[1], aR[2], aR[3]);
            *reinterpret_cast<float4*>(xp + PL + o)     = make_float4(aZ[0], aZ[1], aZ[2], aZ[3]);
            *reinterpret_cast<float4*>(xp + 2*PL + o)   = make_float4(aN[0], aN[1], aN[2], aN[3]);
        }
    }
}

// ---------------- Phase 2: barrier-free single-wave scan ----------------
__global__ __launch_bounds__(256, 1)
void gru_scan_lane(const float* __restrict__ xp,
                   const float* __restrict__ h0,
                   const float* __restrict__ w_hh,
                   const float* __restrict__ b_hh,
                   float* __restrict__ out,
                   float* __restrict__ h_state,
                   int t0, int tlen)
{
    const int tid = threadIdx.x, w = tid >> 6, j = tid & 63;
    const int u = blockIdx.x * 4 + w, b = u >> 3, g = u & 7;

    __shared__ __align__(16) _Float16 hlds[4][2][64];   // per-wave h double-buffer

    // Weight rows {j, 64+j, 128+j} of W_hh[g], fp16-packed, exp2-prescaled.
    h2 WR[32], WZ[32], WN[32];
    {
        const float4* rp = reinterpret_cast<const float4*>(w_hh + ((size_t)g*K3_ + j) * 64);
        const float4* zp = reinterpret_cast<const float4*>(w_hh + ((size_t)g*K3_ + 64 + j) * 64);
        const float4* np = reinterpret_cast<const float4*>(w_hh + ((size_t)g*K3_ + 128 + j) * 64);
        #pragma unroll
        for (int q = 0; q < 16; ++q) {
            float4 a = rp[q];
            WR[2*q]   = h2{(_Float16)(L2E_*a.x),  (_Float16)(L2E_*a.y)};
            WR[2*q+1] = h2{(_Float16)(L2E_*a.z),  (_Float16)(L2E_*a.w)};
            a = zp[q];
            WZ[2*q]   = h2{(_Float16)(L2E_*a.x),  (_Float16)(L2E_*a.y)};
            WZ[2*q+1] = h2{(_Float16)(L2E_*a.z),  (_Float16)(L2E_*a.w)};
            a = np[q];
            WN[2*q]   = h2{(_Float16)(L2E2_*a.x), (_Float16)(L2E2_*a.y)};
            WN[2*q+1] = h2{(_Float16)(L2E2_*a.z), (_Float16)(L2E2_*a.w)};
        }
    }
    const float bhn = b_hh[g * K3_ + 128 + j] * L2E2_;

    float hc = (t0 == 0) ? h0[((size_t)g * B_ + b) * 64 + j]
                         : h_state[u * 64 + j];
    hlds[w][0][j] = (_Float16)hc;

    const size_t PL = (size_t)tlen * NU_ * 64, ST = (size_t)NU_ * 64;
    const size_t base = (size_t)u * 64 + j;
    const float* XR = xp + base;
    const float* XZ = xp + PL + base;
    const float* XN = xp + 2 * PL + base;
    float* outp = out + ((size_t)b * 512 + g * 64 + j) * T_ + t0;

    asm volatile("s_waitcnt lgkmcnt(0)" ::: "memory");   // h(0) visible in-wave

    // Depth-2 rotating xp prefetch (named slots A/B; slot = U&1)
    float xrA = XR[0], xzA = XZ[0], xnA = XN[0];
    float xrB = XR[ST], xzB = XZ[ST], xnB = XN[ST];

    float hist[8];

    // One step. U literal -> all indices static. Wave-synchronous:
    // reads (buf U&1, broadcast) -> 6-chain fdot2 -> gates (6 TRANS) ->
    // write b16 to buf^1 -> refill xp slot (t+2) -> lgkmcnt(0).
    #define SSTEP(U, XRs, XZs, XNs) do {                                          \
        const int curb = (U) & 1;                                                 \
        const float4* hp = reinterpret_cast<const float4*>(&hlds[w][curb][0]);    \
        h2 hv[32];                                                                \
        _Pragma("unroll")                                                         \
        for (int q = 0; q < 8; ++q) {                                             \
            float4 Hq = hp[q];                                                    \
            hv[4*q+0] = __builtin_bit_cast(h2, Hq.x);                             \
            hv[4*q+1] = __builtin_bit_cast(h2, Hq.y);                             \
            hv[4*q+2] = __builtin_bit_cast(h2, Hq.z);                             \
            hv[4*q+3] = __builtin_bit_cast(h2, Hq.w);                             \
        }                                                                         \
        float hr0=0.f, hr1=0.f, hz0=0.f, hz1=0.f, hn0=0.f, hn1=0.f;               \
        _Pragma("unroll")                                                         \
        for (int i = 0; i < 16; ++i) {                                            \
            hr0 = fdot2_(WR[i],    hv[i],    hr0);                                \
            hr1 = fdot2_(WR[16+i], hv[16+i], hr1);                                \
            hz0 = fdot2_(WZ[i],    hv[i],    hz0);                                \
            hz1 = fdot2_(WZ[16+i], hv[16+i], hz1);                                \
            hn0 = fdot2_(WN[i],    hv[i],    hn0);                                \
            hn1 = fdot2_(WN[16+i], hv[16+i], hn1);                                \
        }                                                                         \
        const float rr = __builtin_amdgcn_rcpf(1.0f + exp2_f(-(hr0+hr1+XRs)));    \
        const float zz = __builtin_amdgcn_rcpf(1.0f + exp2_f(-(hz0+hz1+XZs)));    \
        const float pn = XNs + rr * (hn0 + hn1 + bhn);                            \
        const float nn = 1.0f - 2.0f * __builtin_amdgcn_rcpf(exp2_f(pn) + 1.0f);  \
        hc = nn + zz * (hc - nn);                                                 \
        hist[U] = hc;                                                             \
        hlds[w][curb ^ 1][j] = (_Float16)hc;                                      \
        int tn = tg + (U) + 2; if (tn > tlen - 1) tn = tlen - 1;                  \
        XRs = XR[(size_t)tn * ST];                                                \
        XZs = XZ[(size_t)tn * ST];                                                \
        XNs = XN[(size_t)tn * ST];                                                \
        asm volatile("s_waitcnt lgkmcnt(0)" ::: "memory");                        \
    } while (0)

    const int ngrp = tlen / 8;
    for (int grp = 0; grp < ngrp; ++grp) {
        const int tg = grp * 8;
        SSTEP(0, xrA, xzA, xnA); SSTEP(1, xrB, xzB, xnB);
        SSTEP(2, xrA, xzA, xnA); SSTEP(3, xrB, xzB, xnB);
        SSTEP(4, xrA, xzA, xnA); SSTEP(5, xrB, xzB, xnB);
        SSTEP(6, xrA, xzA, xnA); SSTEP(7, xrB, xzB, xnB);
        // Coalesced 8-step flush (32B, aligned: 16 | 8000 and 8 | tg)
        *reinterpret_cast<float4*>(outp + tg)     = make_float4(hist[0], hist[1], hist[2], hist[3]);
        *reinterpret_cast<float4*>(outp + tg + 4) = make_float4(hist[4], hist[5], hist[6], hist[7]);
    }
    #undef SSTEP

    h_state[u * 64 + j] = hc;
}

// ---------------- Host ----------------
extern "C" void kernel_launch(void* const* d_in, const int* in_sizes, int n_in,
                              void* d_out, int out_size, void* d_ws, size_t ws_size,
                              hipStream_t stream)
{
    const float* x    = (const float*)d_in[0];
    const float* h0   = (const float*)d_in[1];
    const float* w_ih = (const float*)d_in[2];
    const float* w_hh = (const float*)d_in[3];
    const float* b_ih = (const float*)d_in[4];
    const float* b_hh = (const float*)d_in[5];
    float* out = (float*)d_out;

    // tlen: multiple of 8, divides 2000. Single xp buffer (stream is serial).
    const int cand[6] = {2000, 1000, 400, 200, 40, 8};
    int tlen = 8;
    for (int i = 0; i < 6; ++i) {
        size_t need = 3ull * cand[i] * NU_ * 64 * 4 + 65536;
        if (need <= ws_size) { tlen = cand[i]; break; }
    }
    float* xp = (float*)d_ws;
    float* h_state = (float*)((char*)d_ws + 3ull * tlen * NU_ * 64 * 4);

    for (int t0 = 0; t0 < T_; t0 += tlen) {
        gru_xproj<<<NU_, 256, 0, stream>>>(x, w_ih, b_ih, b_hh, xp, t0, tlen);
        gru_scan_lane<<<64, 256, 0, stream>>>(xp, h0, w_hh, b_hh, out, h_state, t0, tlen);
    }
}